// Round 1
// baseline (537.817 us; speedup 1.0000x reference)
//
#include <hip/hip_runtime.h>
#include <hip/hip_bf16.h>
#include <math.h>

#define B 16
#define N 512
#define L 512
#define DIM 10
#define DM 128
#define H 8
#define DK 16
#define DFF 512
#define LG 3
#define LO 3
#define NEGV -9.0e15f
#define TI 8
#define RQ 8
#define QCH 128

__device__ __forceinline__ float wave_reduce_max(float v) {
    #pragma unroll
    for (int o = 32; o > 0; o >>= 1) v = fmaxf(v, __shfl_down(v, o, 64));
    return v;
}
__device__ __forceinline__ float wave_reduce_sum(float v) {
    #pragma unroll
    for (int o = 32; o > 0; o >>= 1) v += __shfl_down(v, o, 64);
    return v;
}

// ---------------- GNN ----------------

__global__ void k_embed_fp(const int* __restrict__ fing, const float* __restrict__ emb_fp,
                           float* __restrict__ xs) {
    int idx = blockIdx.x * blockDim.x + threadIdx.x;
    if (idx >= B * N * DIM) return;
    int d = idx % DIM;
    int bn = idx / DIM;
    xs[idx] = emb_fp[fing[bn] * DIM + d];
}

__global__ void k_gnn_h(const float* __restrict__ xs, const float* __restrict__ fp_mask,
                        const float* __restrict__ Wg, const float* __restrict__ bg,
                        const float* __restrict__ aatt,
                        float* __restrict__ h, float* __restrict__ s1, float* __restrict__ s2) {
    int bn = blockIdx.x * blockDim.x + threadIdx.x;
    if (bn >= B * N) return;
    float x[DIM];
    #pragma unroll
    for (int d = 0; d < DIM; d++) x[d] = xs[bn * DIM + d];
    float m = fp_mask[bn];
    float a1 = 0.f, a2 = 0.f;
    #pragma unroll
    for (int j = 0; j < DIM; j++) {
        float acc = bg[j];
        #pragma unroll
        for (int d = 0; d < DIM; d++) acc += x[d] * Wg[d * DIM + j];
        acc = fmaxf(acc, 0.f) * m;
        h[bn * DIM + j] = acc;
        a1 += acc * aatt[j];
        a2 += acc * aatt[DIM + j];
    }
    s1[bn] = a1;
    s2[bn] = a2;
}

// one block handles TI=8 rows of one batch; 256 threads
__global__ void k_gnn_att(const float* __restrict__ h, const float* __restrict__ s1,
                          const float* __restrict__ s2, const int* __restrict__ adj,
                          float* __restrict__ xs) {
    int b  = blockIdx.x / (N / TI);
    int ig = blockIdx.x % (N / TI);
    int t = threadIdx.x;
    int wid = t >> 6, lane = t & 63;

    __shared__ float h_s[N * DIM];   // 20KB
    __shared__ float s2_s[N];        // 2KB
    __shared__ float redm[4];
    __shared__ float red[4][DIM + 1];

    const float* hb = h + (long)b * N * DIM;
    for (int i = t; i < N * DIM; i += 256) h_s[i] = hb[i];
    for (int j = t; j < N; j += 256) s2_s[j] = s2[b * N + j];
    __syncthreads();

    for (int r = 0; r < TI; r++) {
        int i = ig * TI + r;
        float s1v = s1[b * N + i];
        const int* adjrow = adj + ((long)b * N + i) * N;

        float sc[2];
        #pragma unroll
        for (int u = 0; u < 2; u++) {
            int j = t + u * 256;
            float e = s1v + s2_s[j];
            e = e > 0.f ? e : 0.01f * e;
            sc[u] = (adjrow[j] > 0) ? e : NEGV;
        }
        float lm = fmaxf(sc[0], sc[1]);
        lm = wave_reduce_max(lm);
        if (lane == 0) redm[wid] = lm;
        __syncthreads();
        float m = fmaxf(fmaxf(redm[0], redm[1]), fmaxf(redm[2], redm[3]));

        float lsum = 0.f;
        float lacc[DIM];
        #pragma unroll
        for (int d = 0; d < DIM; d++) lacc[d] = 0.f;
        #pragma unroll
        for (int u = 0; u < 2; u++) {
            int j = t + u * 256;
            float p = expf(sc[u] - m);
            lsum += p;
            #pragma unroll
            for (int d = 0; d < DIM; d++) lacc[d] += p * h_s[j * DIM + d];
        }
        lsum = wave_reduce_sum(lsum);
        #pragma unroll
        for (int d = 0; d < DIM; d++) lacc[d] = wave_reduce_sum(lacc[d]);
        if (lane == 0) {
            red[wid][0] = lsum;
            #pragma unroll
            for (int d = 0; d < DIM; d++) red[wid][1 + d] = lacc[d];
        }
        __syncthreads();
        if (t < DIM) {
            float sum = red[0][0] + red[1][0] + red[2][0] + red[3][0];
            float a   = red[0][1 + t] + red[1][1 + t] + red[2][1 + t] + red[3][1 + t];
            xs[((long)b * N + i) * DIM + t] += a / sum;
        }
        __syncthreads();
    }
}

__global__ void k_compound(const float* __restrict__ xs, const float* __restrict__ fp_mask,
                           const float* __restrict__ Watt, const float* __restrict__ batt,
                           float* __restrict__ compound, float* __restrict__ hc) {
    int b = blockIdx.x;
    int t = threadIdx.x;  // 256
    int wid = t >> 6, lane = t & 63;
    float lacc[DIM];
    #pragma unroll
    for (int d = 0; d < DIM; d++) lacc[d] = 0.f;
    for (int n = t; n < N; n += 256) {
        float m = fp_mask[b * N + n];
        #pragma unroll
        for (int d = 0; d < DIM; d++) lacc[d] += xs[((long)b * N + n) * DIM + d] * m;
    }
    __shared__ float red[4][DIM];
    __shared__ float comp_s[DIM];
    #pragma unroll
    for (int d = 0; d < DIM; d++) lacc[d] = wave_reduce_sum(lacc[d]);
    if (lane == 0) {
        #pragma unroll
        for (int d = 0; d < DIM; d++) red[wid][d] = lacc[d];
    }
    __syncthreads();
    if (t < DIM) {
        float c = (red[0][t] + red[1][t] + red[2][t] + red[3][t]) / (float)N;
        compound[b * DIM + t] = c;
        comp_s[t] = c;
    }
    __syncthreads();
    if (t < DIM) {
        float acc = batt[t];
        #pragma unroll
        for (int e = 0; e < DIM; e++) acc += comp_s[e] * Watt[e * DIM + t];
        hc[b * DIM + t] = fmaxf(acc, 0.f);
    }
}

// ---------------- Transformer ----------------

__global__ void k_pe(float* __restrict__ pe) {
    int idx = blockIdx.x * blockDim.x + threadIdx.x;
    if (idx >= L * DM) return;
    int d = idx % DM, l = idx / DM;
    int k = d >> 1;
    double div = exp((double)(2 * k) * (-log(10000.0) / (double)DM));
    double ang = (double)l * div;
    pe[idx] = (d & 1) ? (float)cos(ang) : (float)sin(ang);
}

__global__ void k_embed_word(const int* __restrict__ words, const float* __restrict__ emb,
                             const float* __restrict__ pe, float* __restrict__ x) {
    long idx = (long)blockIdx.x * blockDim.x + threadIdx.x;
    if (idx >= (long)B * L * DM) return;
    int d = idx % DM;
    long bl = idx / DM;
    int l = (int)(bl % L);
    x[idx] = emb[(long)words[bl] * DM + d] * sqrtf(128.0f) + pe[l * DM + d];
}

__global__ void k_layernorm(const float* __restrict__ x, const float* __restrict__ g,
                            const float* __restrict__ bb, float* __restrict__ out) {
    int row = blockIdx.x;
    int t = threadIdx.x;  // 128
    int wid = t >> 6, lane = t & 63;
    float v = x[(long)row * DM + t];
    float s = wave_reduce_sum(v);
    __shared__ float r2[2], r3[2];
    if (lane == 0) r2[wid] = s;
    __syncthreads();
    float mean = (r2[0] + r2[1]) / (float)DM;
    float dv = v - mean;
    float q = wave_reduce_sum(dv * dv);
    if (lane == 0) r3[wid] = q;
    __syncthreads();
    float sd = sqrtf((r3[0] + r3[1]) / (float)(DM - 1)) + 1e-6f;
    out[(long)row * DM + t] = g[t] * dv / sd + bb[t];
}

// 8 rows per block, 384 threads: thread = (proj, out-col)
__global__ void k_qkv(const float* __restrict__ xn,
                      const float* __restrict__ Wq, const float* __restrict__ bq,
                      const float* __restrict__ Wk, const float* __restrict__ bk,
                      const float* __restrict__ Wv, const float* __restrict__ bv,
                      float* __restrict__ q, float* __restrict__ k, float* __restrict__ v) {
    long row0 = (long)blockIdx.x * RQ;
    int t = threadIdx.x;  // 384
    __shared__ float xs_s[RQ * DM];
    for (int i = t; i < RQ * DM; i += 384) xs_s[i] = xn[row0 * DM + i];
    __syncthreads();
    int proj = t / DM;
    int j = t % DM;
    const float* W    = proj == 0 ? Wq : (proj == 1 ? Wk : Wv);
    const float* bias = proj == 0 ? bq : (proj == 1 ? bk : bv);
    float* out        = proj == 0 ? q  : (proj == 1 ? k  : v);
    float acc[RQ];
    #pragma unroll
    for (int r = 0; r < RQ; r++) acc[r] = bias[j];
    for (int d = 0; d < DM; d++) {
        float w = W[d * DM + j];
        #pragma unroll
        for (int r = 0; r < RQ; r++) acc[r] += xs_s[r * DM + d] * w;
    }
    #pragma unroll
    for (int r = 0; r < RQ; r++) {
        long row = row0 + r;
        int b = (int)(row / L), l = (int)(row % L);
        out[(((long)b * H + j / DK) * L + l) * DK + (j % DK)] = acc[r];
    }
}

__global__ void k_attn(const float* __restrict__ q, const float* __restrict__ k,
                       const float* __restrict__ v, const float* __restrict__ wmask,
                       float* __restrict__ attnout) {
    int blk = blockIdx.x;                 // B*H*(L/QCH)
    int qc = blk % (L / QCH);
    int bh = blk / (L / QCH);
    int b = bh / H, hh = bh % H;
    int t = threadIdx.x;                  // 128
    __shared__ float4 k_s[L * DK / 4];    // 32KB
    __shared__ float4 v_s[L * DK / 4];    // 32KB
    const float4* kb4 = (const float4*)(k + (long)bh * L * DK);
    const float4* vb4 = (const float4*)(v + (long)bh * L * DK);
    for (int i = t; i < L * DK / 4; i += QCH) { k_s[i] = kb4[i]; v_s[i] = vb4[i]; }
    __syncthreads();

    int l = qc * QCH + t;
    const float4* qrow = (const float4*)(q + ((long)bh * L + l) * DK);
    float4 qr[4];
    #pragma unroll
    for (int u = 0; u < 4; u++) {
        qr[u] = qrow[u];
        qr[u].x *= 0.25f; qr[u].y *= 0.25f; qr[u].z *= 0.25f; qr[u].w *= 0.25f;
    }
    float m = -1e30f, ssum = 0.f;
    float4 acc[4];
    #pragma unroll
    for (int u = 0; u < 4; u++) acc[u] = make_float4(0.f, 0.f, 0.f, 0.f);
    const float* wm = wmask + (long)b * L;
    for (int j = 0; j < L; j++) {
        float s = 0.f;
        #pragma unroll
        for (int u = 0; u < 4; u++) {
            float4 kk = k_s[j * 4 + u];
            s += qr[u].x * kk.x + qr[u].y * kk.y + qr[u].z * kk.z + qr[u].w * kk.w;
        }
        s = (wm[j] > 0.f) ? s : -1e9f;
        float mn = fmaxf(m, s);
        float scale = expf(m - mn);
        float p = expf(s - mn);
        ssum = ssum * scale + p;
        #pragma unroll
        for (int u = 0; u < 4; u++) {
            float4 vv = v_s[j * 4 + u];
            acc[u].x = acc[u].x * scale + p * vv.x;
            acc[u].y = acc[u].y * scale + p * vv.y;
            acc[u].z = acc[u].z * scale + p * vv.z;
            acc[u].w = acc[u].w * scale + p * vv.w;
        }
        m = mn;
    }
    float inv = 1.f / ssum;
    float4* out = (float4*)(attnout + ((long)b * L + l) * DM + hh * DK);
    #pragma unroll
    for (int u = 0; u < 4; u++) {
        out[u] = make_float4(acc[u].x * inv, acc[u].y * inv, acc[u].z * inv, acc[u].w * inv);
    }
}

// x += attnout @ Wo + bo ; 8 rows/block, 128 threads
__global__ void k_oproj(const float* __restrict__ attnout, const float* __restrict__ Wo,
                        const float* __restrict__ bo, float* __restrict__ x) {
    long row0 = (long)blockIdx.x * RQ;
    int t = threadIdx.x;  // 128
    __shared__ float a_s[RQ * DM];
    for (int i = t; i < RQ * DM; i += 128) a_s[i] = attnout[row0 * DM + i];
    __syncthreads();
    float acc[RQ];
    #pragma unroll
    for (int r = 0; r < RQ; r++) acc[r] = bo[t];
    for (int d = 0; d < DM; d++) {
        float w = Wo[d * DM + t];
        #pragma unroll
        for (int r = 0; r < RQ; r++) acc[r] += a_s[r * DM + d] * w;
    }
    #pragma unroll
    for (int r = 0; r < RQ; r++) x[(row0 + r) * DM + t] += acc[r];
}

// fused FFN: x += relu(xn@W1+b1)@W2+b2 ; 8 rows/block, 512 threads
__global__ void k_ffn(const float* __restrict__ xn, const float* __restrict__ W1,
                      const float* __restrict__ b1, const float* __restrict__ W2,
                      const float* __restrict__ b2, float* __restrict__ x) {
    long row0 = (long)blockIdx.x * RQ;
    int t = threadIdx.x;  // 512
    __shared__ float xs_s[RQ * DM];    // 4KB
    __shared__ float h_s[RQ * DFF];    // 16KB
    __shared__ float red_s[512];
    for (int i = t; i < RQ * DM; i += 512) xs_s[i] = xn[row0 * DM + i];
    __syncthreads();
    {
        float acc[RQ];
        #pragma unroll
        for (int r = 0; r < RQ; r++) acc[r] = b1[t];
        for (int d = 0; d < DM; d++) {
            float w = W1[d * DFF + t];
            #pragma unroll
            for (int r = 0; r < RQ; r++) acc[r] += xs_s[r * DM + d] * w;
        }
        #pragma unroll
        for (int r = 0; r < RQ; r++) h_s[r * DFF + t] = fmaxf(acc[r], 0.f);
    }
    __syncthreads();
    int col = t & 127, seg = t >> 7;
    float acc2[RQ];
    #pragma unroll
    for (int r = 0; r < RQ; r++) acc2[r] = (seg == 0) ? b2[col] : 0.f;
    for (int f = seg * 128; f < seg * 128 + 128; f++) {
        float w = W2[f * DM + col];
        #pragma unroll
        for (int r = 0; r < RQ; r++) acc2[r] += h_s[r * DFF + f] * w;
    }
    for (int r = 0; r < RQ; r++) {
        red_s[t] = acc2[r];
        __syncthreads();
        if (t < 128) {
            float sum = red_s[t] + red_s[t + 128] + red_s[t + 256] + red_s[t + 384];
            x[(row0 + r) * DM + t] += sum;
        }
        __syncthreads();
    }
}

// lnf -> relu -> Wtout -> Watt/relu -> hp ; per row, 128 threads
__global__ void k_lnf_hp(const float* __restrict__ x, const float* __restrict__ g,
                         const float* __restrict__ bb, const float* __restrict__ Wtout,
                         const float* __restrict__ btout, const float* __restrict__ Watt,
                         const float* __restrict__ batt, float* __restrict__ hp) {
    int row = blockIdx.x;
    int t = threadIdx.x;  // 128
    int wid = t >> 6, lane = t & 63;
    float v = x[(long)row * DM + t];
    float s = wave_reduce_sum(v);
    __shared__ float r2[2], r3[2];
    if (lane == 0) r2[wid] = s;
    __syncthreads();
    float mean = (r2[0] + r2[1]) / (float)DM;
    float dv = v - mean;
    float qq = wave_reduce_sum(dv * dv);
    if (lane == 0) r3[wid] = qq;
    __syncthreads();
    float sd = sqrtf((r3[0] + r3[1]) / (float)(DM - 1)) + 1e-6f;
    float xnv = g[t] * dv / sd + bb[t];
    __shared__ float rrelu[DM];
    rrelu[t] = fmaxf(xnv, 0.f);
    __syncthreads();
    __shared__ float wv_s[DIM];
    if (t < DIM) {
        float acc = btout[t];
        for (int d = 0; d < DM; d++) acc += rrelu[d] * Wtout[d * DIM + t];
        wv_s[t] = acc;
    }
    __syncthreads();
    if (t < DIM) {
        float acc = batt[t];
        #pragma unroll
        for (int e = 0; e < DIM; e++) acc += wv_s[e] * Watt[e * DIM + t];
        hp[(long)row * DIM + t] = fmaxf(acc, 0.f);
    }
}

__global__ void k_final(const float* __restrict__ hp, const float* __restrict__ hc,
                        const float* __restrict__ compound, const float* __restrict__ Wout,
                        const float* __restrict__ bout, const float* __restrict__ Wint,
                        const float* __restrict__ bint, float* __restrict__ out) {
    int b = blockIdx.x;
    int t = threadIdx.x;  // 256
    int wid = t >> 6, lane = t & 63;
    __shared__ float hc_s[DIM];
    if (t < DIM) hc_s[t] = hc[b * DIM + t];
    __syncthreads();
    float lacc[DIM];
    #pragma unroll
    for (int e = 0; e < DIM; e++) lacc[e] = 0.f;
    for (int l = t; l < L; l += 256) {
        const float* hpl = hp + ((long)b * L + l) * DIM;
        float hv[DIM];
        float dot = 0.f;
        #pragma unroll
        for (int e = 0; e < DIM; e++) { hv[e] = hpl[e]; dot += hc_s[e] * hv[e]; }
        float w = tanhf(dot);
        #pragma unroll
        for (int e = 0; e < DIM; e++) lacc[e] += w * hv[e];
    }
    __shared__ float red[4][DIM];
    #pragma unroll
    for (int e = 0; e < DIM; e++) lacc[e] = wave_reduce_sum(lacc[e]);
    if (lane == 0) {
        #pragma unroll
        for (int e = 0; e < DIM; e++) red[wid][e] = lacc[e];
    }
    __syncthreads();
    if (t == 0) {
        float cat[2 * DIM], tmp[2 * DIM];
        for (int e = 0; e < DIM; e++) cat[e] = compound[b * DIM + e];
        for (int e = 0; e < DIM; e++)
            cat[DIM + e] = (red[0][e] + red[1][e] + red[2][e] + red[3][e]) / (float)L;
        for (int j = 0; j < LO; j++) {
            const float* W = Wout + j * 2 * DIM * 2 * DIM;
            const float* bj = bout + j * 2 * DIM;
            for (int o = 0; o < 2 * DIM; o++) {
                float acc = bj[o];
                for (int e = 0; e < 2 * DIM; e++) acc += cat[e] * W[e * 2 * DIM + o];
                tmp[o] = fmaxf(acc, 0.f);
            }
            for (int o = 0; o < 2 * DIM; o++) cat[o] = tmp[o];
        }
        float o0 = bint[0], o1 = bint[1];
        for (int e = 0; e < 2 * DIM; e++) {
            o0 += cat[e] * Wint[e * 2 + 0];
            o1 += cat[e] * Wint[e * 2 + 1];
        }
        out[b * 2 + 0] = o0;
        out[b * 2 + 1] = o1;
    }
}

extern "C" void kernel_launch(void* const* d_in, const int* in_sizes, int n_in,
                              void* d_out, int out_size, void* d_ws, size_t ws_size,
                              hipStream_t stream) {
    (void)in_sizes; (void)n_in; (void)out_size; (void)ws_size;
    const int*   fingerprints = (const int*)d_in[0];
    const float* fp_mask      = (const float*)d_in[1];
    const int*   adjacency    = (const int*)d_in[2];
    const int*   words        = (const int*)d_in[3];
    const float* words_mask   = (const float*)d_in[4];
    const float* emb_fp       = (const float*)d_in[5];
    const float* emb_word     = (const float*)d_in[6];
    const float* Wg   = (const float*)d_in[7];
    const float* bg   = (const float*)d_in[8];
    const float* attn_a = (const float*)d_in[9];
    const float* Wq = (const float*)d_in[10];
    const float* bq = (const float*)d_in[11];
    const float* Wk = (const float*)d_in[12];
    const float* bk = (const float*)d_in[13];
    const float* Wv = (const float*)d_in[14];
    const float* bv = (const float*)d_in[15];
    const float* Wo = (const float*)d_in[16];
    const float* bo = (const float*)d_in[17];
    const float* ln1_g = (const float*)d_in[18];
    const float* ln1_b = (const float*)d_in[19];
    const float* ln2_g = (const float*)d_in[20];
    const float* ln2_b = (const float*)d_in[21];
    const float* lnf_g = (const float*)d_in[22];
    const float* lnf_b = (const float*)d_in[23];
    const float* W1 = (const float*)d_in[24];
    const float* b1 = (const float*)d_in[25];
    const float* W2 = (const float*)d_in[26];
    const float* b2 = (const float*)d_in[27];
    const float* Wtout = (const float*)d_in[28];
    const float* btout = (const float*)d_in[29];
    const float* Watt  = (const float*)d_in[30];
    const float* batt  = (const float*)d_in[31];
    const float* Wout  = (const float*)d_in[32];
    const float* bout  = (const float*)d_in[33];
    const float* Wint  = (const float*)d_in[34];
    const float* bint  = (const float*)d_in[35];
    float* out = (float*)d_out;

    float* w = (float*)d_ws;
    float* xs = w;        w += B * N * DIM;
    float* h  = w;        w += B * N * DIM;
    float* s1 = w;        w += B * N;
    float* s2 = w;        w += B * N;
    float* compound = w;  w += B * DIM;
    float* hc = w;        w += B * DIM;
    float* pe = w;        w += L * DM;
    float* x  = w;        w += (long)B * L * DM;
    float* xn = w;        w += (long)B * L * DM;
    float* qb = w;        w += (long)B * H * L * DK;
    float* kb = w;        w += (long)B * H * L * DK;
    float* vb = w;        w += (long)B * H * L * DK;
    float* attnout = w;   w += (long)B * L * DM;
    float* hp = w;        w += (long)B * L * DIM;

    // ---- GNN ----
    k_embed_fp<<<(B * N * DIM + 255) / 256, 256, 0, stream>>>(fingerprints, emb_fp, xs);
    for (int i = 0; i < LG; i++) {
        k_gnn_h<<<(B * N + 255) / 256, 256, 0, stream>>>(
            xs, fp_mask, Wg + i * DIM * DIM, bg + i * DIM, attn_a + i * 2 * DIM, h, s1, s2);
        k_gnn_att<<<B * (N / TI), 256, 0, stream>>>(h, s1, s2, adjacency, xs);
    }
    k_compound<<<B, 256, 0, stream>>>(xs, fp_mask, Watt, batt, compound, hc);

    // ---- Transformer ----
    k_pe<<<(L * DM + 255) / 256, 256, 0, stream>>>(pe);
    k_embed_word<<<(B * L * DM + 255) / 256, 256, 0, stream>>>(words, emb_word, pe, x);
    k_layernorm<<<B * L, DM, 0, stream>>>(x, ln1_g, ln1_b, xn);
    k_qkv<<<B * L / RQ, 3 * DM, 0, stream>>>(xn, Wq, bq, Wk, bk, Wv, bv, qb, kb, vb);
    k_attn<<<B * H * (L / QCH), QCH, 0, stream>>>(qb, kb, vb, words_mask, attnout);
    k_oproj<<<B * L / RQ, DM, 0, stream>>>(attnout, Wo, bo, x);
    k_layernorm<<<B * L, DM, 0, stream>>>(x, ln2_g, ln2_b, xn);
    k_ffn<<<B * L / RQ, DFF, 0, stream>>>(xn, W1, b1, W2, b2, x);
    k_lnf_hp<<<B * L, DM, 0, stream>>>(x, lnf_g, lnf_b, Wtout, btout, Watt, batt, hp);
    k_final<<<B, 256, 0, stream>>>(hp, hc, compound, Wout, bout, Wint, bint, out);
}